// Round 16
// baseline (83.880 us; speedup 1.0000x reference)
//
#include <hip/hip_runtime.h>
#include <math.h>

#define Bb 2
#define Lq 512
#define CS 384
#define CZ 128
#define Hh 8
#define HD 16
#define NEG_MAX -3.4028234663852886e38f
#define LOG2_THETA 13.287712379549449f

typedef float f2_t __attribute__((ext_vector_type(2)));
typedef float f4_t __attribute__((ext_vector_type(4)));

__device__ inline float wave_reduce_sum(float v) {
    #pragma unroll
    for (int off = 32; off > 0; off >>= 1) v += __shfl_xor(v, off, 64);
    return v;
}
__device__ inline float wave_reduce_max(float v) {
    #pragma unroll
    for (int off = 32; off > 0; off >>= 1) v = fmaxf(v, __shfl_xor(v, off, 64));
    return v;
}
__device__ inline void wave_reduce_sum2(float& a, float& b) {
    #pragma unroll
    for (int off = 32; off > 0; off >>= 1) {
        a += __shfl_xor(a, off, 64);
        b += __shfl_xor(b, off, 64);
    }
}

// Transpose weights once: WsT[k][c] = W_s[c][k]; WqkT[k][j] = W_qk[j][k].
__global__ __launch_bounds__(256) void k_tr(const float* __restrict__ Ws,
        const float* __restrict__ Wqk, float* __restrict__ WsT, float* __restrict__ WqkT) {
    int bid = blockIdx.x, t = threadIdx.x;
    if (bid < 128) {
        int c = bid;
        for (int k = t; k < CS; k += 256) WsT[k*CZ + c] = Ws[c*CS + k];
    } else {
        int j0 = (bid - 128) * 2;
        if (t < 128) WqkT[t*(2*CZ) + j0] = Wqk[j0*CZ + t];
        else         WqkT[(t-128)*(2*CZ) + j0 + 1] = Wqk[(j0+1)*CZ + (t-128)];
    }
}

// k_proj3: coalesced weights + OCCUPANCY (512 blocks x 2 rows = 2 blocks/CU, 8 waves/CU).
// x phase: 4-way split-k, wave = one k-quarter, 512B-coalesced WsT loads.
// qk phase: thread owns RoPE pair (j2, j2+1), coalesced f2 WqkT loads, in-register RoPE.
__global__ __launch_bounds__(256) void k_proj3(const float* __restrict__ s,
        const float* __restrict__ WsT, const float* __restrict__ g_s,
        const float* __restrict__ WqkT, float* __restrict__ qk_ws) {
    int blk = blockIdx.x;            // rows blk*2, blk*2+1
    int t = threadIdx.x;             // 0..255
    __shared__ float s_lds[2*CS];
    __shared__ float x_lds[2*CZ];
    __shared__ float red2[4][2*CZ];  // split-k partials (4 KB)
    __shared__ float red[4];
    size_t base = (size_t)blk * 2 * CS;
    for (int i = t; i < 2*CS; i += 256) s_lds[i] = s[base + i];
    __syncthreads();

    // ---- x matmul: 4-way split-k. thread (c4=(t&31)*4, r=(t>>5)&1, kh=t>>6) ----
    {
        int c4 = (t & 31) * 4, r = (t >> 5) & 1, kh = t >> 6;
        const float* wbase = WsT + c4;
        const float* srow  = s_lds + r * CS;
        f4_t acc = {0.f, 0.f, 0.f, 0.f};
        #pragma unroll 4
        for (int i = 0; i < 24; ++i) {
            int k0 = kh*96 + i*4;
            f4_t w0 = *(const f4_t*)(wbase + (size_t)(k0    )*CZ);
            f4_t w1 = *(const f4_t*)(wbase + (size_t)(k0 + 1)*CZ);
            f4_t w2 = *(const f4_t*)(wbase + (size_t)(k0 + 2)*CZ);
            f4_t w3 = *(const f4_t*)(wbase + (size_t)(k0 + 3)*CZ);
            f4_t sv = *(const f4_t*)(srow + k0);
            acc += w0 * sv.x; acc += w1 * sv.y; acc += w2 * sv.z; acc += w3 * sv.w;
        }
        *(f4_t*)&red2[kh][r*CZ + c4] = acc;
    }
    __syncthreads();

    // ---- reduce split-k + rmsnorm. thread (c=t&127, r=t>>7) ----
    {
        int c = t & 127, r = t >> 7;
        float a = red2[0][r*CZ + c] + red2[1][r*CZ + c]
                + red2[2][r*CZ + c] + red2[3][r*CZ + c];
        float ss = wave_reduce_sum(a*a);
        int lane = t & 63, wid = t >> 6;   // waves 0,1 -> row 0; waves 2,3 -> row 1
        if (lane == 0) red[wid] = ss;
        __syncthreads();
        float tot = red[2*r] + red[2*r+1];
        x_lds[r*CZ + c] = a * rsqrtf(tot*(1.f/CZ) + 1e-5f) * g_s[c];
    }
    __syncthreads();

    // ---- qk matmul + in-register RoPE. thread (j2=(t&127)*2, r=t>>7) ----
    {
        int j2 = (t & 127) * 2, r = t >> 7;
        const float* wbase = WqkT + j2;
        const float* xrow  = x_lds + r * CZ;
        f2_t acc = {0.f, 0.f};
        #pragma unroll 8
        for (int k = 0; k < CZ; ++k) {
            f2_t w = *(const f2_t*)(wbase + (size_t)k * (2*CZ));
            acc += w * xrow[k];
        }
        int half = j2 >> 7, within = j2 & 127, h = within >> 4, dd = within & 15;
        int row0 = blk * 2;
        int b = row0 >> 9;
        int l = (row0 + r) & (Lq - 1);
        int d = dd >> 1;
        float inv = exp2f(-(float)(2*d) * (1.f/16.f) * LOG2_THETA);
        float ang = (float)l * inv;
        float cv = cosf(ang), sn = sinf(ang);
        f2_t o;
        o.x = acc.x*cv - acc.y*sn;
        o.y = acc.x*sn + acc.y*cv;
        size_t idx = ((((size_t)half*Bb + b)*Hh + h)*Lq + l)*HD + dd;
        *(f2_t*)(qk_ws + idx) = o;
    }
}

// Fused softmax + output per (b,l). Gram rmsnorm precomputed (phase 1.5).
// Phase 2: half-wave per row, 4 ch/lane, f4 nt stores. (round-12 proven, unchanged)
__global__ __launch_bounds__(512) void k_attn(const float* __restrict__ qk_ws,
        const int* __restrict__ mask, const float* __restrict__ W_o,
        const float* __restrict__ g_z, float* __restrict__ out) {
    int row = blockIdx.x;            // b*512 + l
    int l = row & (Lq - 1);
    int b = row >> 9;
    int t = threadIdx.x;
    int w = t >> 6, lane = t & 63;
    __shared__ float p_lds[Hh][Lq];
    __shared__ float q_lds[CZ];
    __shared__ float g_lds[Hh*Hh];
    __shared__ float sc_lds[Lq];
    if (t < CZ) {
        int qh = t >> 4, dd = t & 15;
        q_lds[t] = qk_ws[(((size_t)b*Hh + qh)*Lq + l)*HD + dd];
    }
    {
        int k = lane & 7, cg = lane >> 3;
        float partial = 0.f;
        #pragma unroll
        for (int cc = 0; cc < 16; ++cc) {
            int cidx = cg*16 + cc;
            partial += W_o[cidx*Hh + w] * W_o[cidx*Hh + k];
        }
        partial += __shfl_xor(partial, 8, 64);
        partial += __shfl_xor(partial, 16, 64);
        partial += __shfl_xor(partial, 32, 64);
        if (lane < 8) g_lds[w*Hh + lane] = partial;
    }
    int maskL = mask[b*Lq + l];
    __syncthreads();

    {
        int h = w;
        const float* kbase = qk_ws + ((((size_t)Bb + b)*Hh + h)*Lq)*HD;
        float q[HD];
        #pragma unroll
        for (int d = 0; d < HD; ++d) q[d] = q_lds[h*HD + d];
        float sv[8];
        float mx = NEG_MAX;
        #pragma unroll
        for (int i = 0; i < 8; ++i) {
            int m = i*64 + lane;
            const float4* k4 = (const float4*)(kbase + (size_t)m * HD);
            float4 k0=k4[0], k1=k4[1], k2=k4[2], k3=k4[3];
            float acc = q[0]*k0.x + q[1]*k0.y + q[2]*k0.z + q[3]*k0.w
                      + q[4]*k1.x + q[5]*k1.y + q[6]*k1.z + q[7]*k1.w
                      + q[8]*k2.x + q[9]*k2.y + q[10]*k2.z + q[11]*k2.w
                      + q[12]*k3.x + q[13]*k3.y + q[14]*k3.z + q[15]*k3.w;
            int pm = maskL & mask[b*Lq + m];
            sv[i] = pm ? acc*0.25f : NEG_MAX;
            mx = fmaxf(mx, sv[i]);
        }
        mx = wave_reduce_max(mx);
        float e[8];
        float sum = 0.f;
        #pragma unroll
        for (int i = 0; i < 8; ++i) { e[i] = __expf(sv[i]-mx); sum += e[i]; }
        sum = wave_reduce_sum(sum);
        float inv = 1.f / sum;
        #pragma unroll
        for (int i = 0; i < 8; ++i) p_lds[h][i*64+lane] = e[i]*inv;
    }
    __syncthreads();

    {
        float p[8];
        #pragma unroll
        for (int k = 0; k < 8; ++k) p[k] = p_lds[k][t];
        float ss = 0.f;
        #pragma unroll
        for (int j = 0; j < 8; ++j) {
            float4 gA = *(const float4*)&g_lds[j*8];
            float4 gB = *(const float4*)&g_lds[j*8 + 4];
            float qj = gA.x*p[0] + gA.y*p[1] + gA.z*p[2] + gA.w*p[3]
                     + gB.x*p[4] + gB.y*p[5] + gB.z*p[6] + gB.w*p[7];
            ss += p[j]*qj;
        }
        sc_lds[t] = rsqrtf(ss*(1.f/CZ) + 1e-5f);
    }

    int g2 = lane >> 5, cl = lane & 31, c0 = cl * 4;
    f4_t wv4[Hh];
    {
        const float4* wp = (const float4*)(W_o + (size_t)c0 * Hh);
        float4 R0a=wp[0], R0b=wp[1], R1a=wp[2], R1b=wp[3];
        float4 R2a=wp[4], R2b=wp[5], R3a=wp[6], R3b=wp[7];
        wv4[0] = f4_t{R0a.x, R1a.x, R2a.x, R3a.x};
        wv4[1] = f4_t{R0a.y, R1a.y, R2a.y, R3a.y};
        wv4[2] = f4_t{R0a.z, R1a.z, R2a.z, R3a.z};
        wv4[3] = f4_t{R0a.w, R1a.w, R2a.w, R3a.w};
        wv4[4] = f4_t{R0b.x, R1b.x, R2b.x, R3b.x};
        wv4[5] = f4_t{R0b.y, R1b.y, R2b.y, R3b.y};
        wv4[6] = f4_t{R0b.z, R1b.z, R2b.z, R3b.z};
        wv4[7] = f4_t{R0b.w, R1b.w, R2b.w, R3b.w};
    }
    f4_t gz4 = *(const f4_t*)(g_z + c0);
    __syncthreads();

    float* obase = out + (size_t)row * Lq * CZ;
    #pragma unroll 1
    for (int i = 0; i < 32; ++i) {
        int m = w*64 + i*2 + g2;
        float pp[Hh];
        #pragma unroll
        for (int k = 0; k < Hh; ++k) pp[k] = p_lds[k][m];
        float sc = sc_lds[m];
        f4_t a = {0.f, 0.f, 0.f, 0.f};
        #pragma unroll
        for (int k = 0; k < Hh; ++k) a += pp[k] * wv4[k];
        a *= sc * gz4;
        __builtin_nontemporal_store(a, (f4_t*)(obase + (size_t)m*CZ + c0));
    }
}

extern "C" void kernel_launch(void* const* d_in, const int* in_sizes, int n_in,
                              void* d_out, int out_size, void* d_ws, size_t ws_size,
                              hipStream_t stream) {
    const float* s    = (const float*)d_in[0];
    const int*   mask = (const int*)d_in[1];
    const float* W_s  = (const float*)d_in[2];
    const float* g_s  = (const float*)d_in[3];
    const float* W_qk = (const float*)d_in[4];
    const float* W_o  = (const float*)d_in[5];
    const float* g_z  = (const float*)d_in[6];
    float* out = (float*)d_out;
    float* ws  = (float*)d_ws;

    // ws layout (floats): qk_ws [0, 262144), WsT [262144, 311296), WqkT [311296, 344064)
    float* qk_ws = ws;
    float* WsT   = ws + 262144;
    float* WqkT  = ws + 311296;

    k_tr<<<256, 256, 0, stream>>>(W_s, W_qk, WsT, WqkT);
    k_proj3<<<512, 256, 0, stream>>>(s, WsT, g_s, WqkT, qk_ws);
    k_attn<<<Bb*Lq, 512, 0, stream>>>(qk_ws, mask, W_o, g_z, out);
}